// Round 1
// baseline (74.815 us; speedup 1.0000x reference)
//
#include <hip/hip_runtime.h>
#include <math.h>

// Quantum circuit collapses to: z_q[b] = r(b)^T A_q r(b), where
//   r(b) = [c0c1, c0s1, s0c1, s0s1], c_i = cos(noise[b][i]*pi/2), s_i = sin(...)
//   A_q  = Re( D^H U^H Z_q U D ),  D = diag(1,-i,-i,-1),
//   U    = product over layers of  C10 * C01 * (I (x) g1) * (g0 (x) I)
// A_q depends only on q_weights (12 floats) -> computed once per block by lane 0.

struct Cx { float re, im; };
__device__ inline Cx cmul(Cx a, Cx b){ return {a.re*b.re - a.im*b.im, a.re*b.im + a.im*b.re}; }
__device__ inline Cx cmadd2(Cx a, Cx x, Cx b, Cx y){
  Cx p = cmul(a,x), q = cmul(b,y);
  return { p.re + q.re, p.im + q.im };
}

__device__ inline float quadform(const float* __restrict__ A,
                                 float r0, float r1, float r2, float r3) {
  float t0 = A[0]*r0  + A[1]*r1  + A[2]*r2  + A[3]*r3;
  float t1 = A[4]*r0  + A[5]*r1  + A[6]*r2  + A[7]*r3;
  float t2 = A[8]*r0  + A[9]*r1  + A[10]*r2 + A[11]*r3;
  float t3 = A[12]*r0 + A[13]*r1 + A[14]*r2 + A[15]*r3;
  return r0*t0 + r1*t1 + r2*t2 + r3*t3;
}

__global__ __launch_bounds__(256) void qc_kernel(const float* __restrict__ noise,
                                                 const float* __restrict__ w,
                                                 float* __restrict__ out,
                                                 int nQuads) {
  __shared__ float sA[32];   // A0[16], A1[16]

  if (threadIdx.x == 0) {
    Cx U[4][4];
    for (int r = 0; r < 4; ++r)
      for (int c = 0; c < 4; ++c)
        U[r][c] = { (r == c) ? 1.f : 0.f, 0.f };

    for (int l = 0; l < 2; ++l) {
      Cx g[2][2][2];  // [wire][i][j]
      for (int q = 0; q < 2; ++q) {
        float phi = w[l*6 + q*3 + 0];
        float th  = w[l*6 + q*3 + 1];
        float om  = w[l*6 + q*3 + 2];
        float st, ct; sincosf(0.5f*th, &st, &ct);
        float sp, cp; sincosf(0.5f*(phi+om), &sp, &cp);
        float sm, cm; sincosf(0.5f*(phi-om), &sm, &cm);
        g[q][0][0] = {  cp*ct, -sp*ct };   //  exp(-i(phi+om)/2) * ct
        g[q][0][1] = { -cm*st, -sm*st };   // -exp(+i(phi-om)/2) * st
        g[q][1][0] = {  cm*st, -sm*st };   //  exp(-i(phi-om)/2) * st
        g[q][1][1] = {  cp*ct,  sp*ct };   //  exp(+i(phi+om)/2) * ct
      }
      // U <- (g0 (x) I) * U   (basis idx = 2*q0 + q1; mixes q0)
      for (int c = 0; c < 4; ++c)
        for (int k = 0; k < 2; ++k) {
          Cx x0 = U[k][c], x1 = U[2+k][c];
          U[k][c]   = cmadd2(g[0][0][0], x0, g[0][0][1], x1);
          U[2+k][c] = cmadd2(g[0][1][0], x0, g[0][1][1], x1);
        }
      // U <- (I (x) g1) * U   (mixes q1)
      for (int c = 0; c < 4; ++c)
        for (int j = 0; j < 2; ++j) {
          Cx x0 = U[2*j][c], x1 = U[2*j+1][c];
          U[2*j][c]   = cmadd2(g[1][0][0], x0, g[1][0][1], x1);
          U[2*j+1][c] = cmadd2(g[1][1][0], x0, g[1][1][1], x1);
        }
      // CNOT(control q0, target q1): swap rows 2 (10) and 3 (11)
      for (int c = 0; c < 4; ++c) { Cx t = U[2][c]; U[2][c] = U[3][c]; U[3][c] = t; }
      // CNOT(control q1, target q0): swap rows 1 (01) and 3 (11)
      for (int c = 0; c < 4; ++c) { Cx t = U[1][c]; U[1][c] = U[3][c]; U[3][c] = t; }
    }

    // V = U * D, D = diag(1, -i, -i, -1); (re,im)*(-i) = (im, -re)
    for (int r = 0; r < 4; ++r) {
      Cx t;
      t = U[r][1]; U[r][1] = {  t.im, -t.re };
      t = U[r][2]; U[r][2] = {  t.im, -t.re };
      t = U[r][3]; U[r][3] = { -t.re, -t.im };
    }

    // A_q[a][b] = sum_r zq[r] * Re( conj(V[r][a]) V[r][b] )
    const float z0s[4] = { 1.f,  1.f, -1.f, -1.f };
    const float z1s[4] = { 1.f, -1.f,  1.f, -1.f };
    for (int a = 0; a < 4; ++a)
      for (int b = 0; b < 4; ++b) {
        float a0 = 0.f, a1 = 0.f;
        for (int r = 0; r < 4; ++r) {
          float d = U[r][a].re*U[r][b].re + U[r][a].im*U[r][b].im;
          a0 += z0s[r]*d;
          a1 += z1s[r]*d;
        }
        sA[a*4 + b]      = a0;
        sA[16 + a*4 + b] = a1;
      }
  }
  __syncthreads();

  float A0[16], A1[16];
  #pragma unroll
  for (int i = 0; i < 16; ++i) { A0[i] = sA[i]; A1[i] = sA[16 + i]; }

  const float4* __restrict__ in4  = (const float4*)noise;
  float4* __restrict__ out4 = (float4*)out;
  const float HPI = 1.57079632679489662f;  // pi/2

  int gid    = blockIdx.x * blockDim.x + threadIdx.x;
  int stride = gridDim.x * blockDim.x;
  for (int i = gid; i < nQuads; i += stride) {
    float4 v = in4[i];   // two samples: (v.x,v.y), (v.z,v.w)
    float4 o;
    {
      float s0, c0, s1, c1;
      __sincosf(v.x * HPI, &s0, &c0);
      __sincosf(v.y * HPI, &s1, &c1);
      float r0 = c0*c1, r1 = c0*s1, r2 = s0*c1, r3 = s0*s1;
      o.x = quadform(A0, r0, r1, r2, r3);
      o.y = quadform(A1, r0, r1, r2, r3);
    }
    {
      float s0, c0, s1, c1;
      __sincosf(v.z * HPI, &s0, &c0);
      __sincosf(v.w * HPI, &s1, &c1);
      float r0 = c0*c1, r1 = c0*s1, r2 = s0*c1, r3 = s0*s1;
      o.z = quadform(A0, r0, r1, r2, r3);
      o.w = quadform(A1, r0, r1, r2, r3);
    }
    out4[i] = o;
  }
}

extern "C" void kernel_launch(void* const* d_in, const int* in_sizes, int n_in,
                              void* d_out, int out_size, void* d_ws, size_t ws_size,
                              hipStream_t stream) {
  const float* noise = (const float*)d_in[0];   // [B,2] float32
  const float* w     = (const float*)d_in[1];   // [2,2,3] float32
  float* out         = (float*)d_out;           // [B,2] float32

  int nQuads = in_sizes[0] / 4;  // B*2 floats -> B/2 float4 chunks
  int threads = 256;
  int blocks  = 1024;            // ~4 quads (8 samples) per thread, grid-stride
  qc_kernel<<<blocks, threads, 0, stream>>>(noise, w, out, nQuads);
}